// Round 4
// baseline (989.288 us; speedup 1.0000x reference)
//
#include <hip/hip_runtime.h>
#include <math.h>

// Problem constants
#define SEQ 384
#define HDIM 768
#define NHEAD 12
#define DHEAD 64
#define GI 4        // i-rows per attn_out block (v reused in registers)
#define LDSB 6400   // scores_pos LDS buffer stride (32*200 floats)

// ---------------------------------------------------------------------------
// Kernel A: fused QKV projection.  C = X @ W + b for W in {Wq,Wk,Wv}
// X staged in LDS (k-panels of 128, transposed), W streamed from L2.
// v4: software-pipelined panel staging — next panel's global loads are
// issued BEFORE the current panel's compute (1 block/CU, 1 wave/SIMD ->
// no TLP to hide the staging; must come from ILP).
// grid (6 mtiles, 12 ntiles, 3 matrices), block 256, tile 64x64.
// ---------------------------------------------------------------------------
__global__ __launch_bounds__(256)
void qkv_gemm(const float* __restrict__ X,
              const float* __restrict__ Wq, const float* __restrict__ bq,
              const float* __restrict__ Wk, const float* __restrict__ bk,
              const float* __restrict__ Wv, const float* __restrict__ bv,
              float* __restrict__ q, float* __restrict__ k, float* __restrict__ v)
{
    __shared__ float Xs[128 * 68];   // [k][m], padded stride 68
    const int z = blockIdx.z;
    const float* W    = (z == 0) ? Wq : (z == 1) ? Wk : Wv;
    const float* bias = (z == 0) ? bq : (z == 1) ? bk : bv;
    float* out        = (z == 0) ? q  : (z == 1) ? k  : v;

    const int m0 = blockIdx.x * 64;
    const int n0 = blockIdx.y * 64;
    const int tid = threadIdx.x;
    const int ty = tid / 16, tx = tid % 16;

    const int lm = tid >> 2;          // 0..63 (m row)
    const int lc = (tid & 3) * 4;     // 0,4,8,12 (k sub-col)

    float acc[4][4] = {};
    float4 xa[8];

    // prefetch panel 0
    #pragma unroll
    for (int it = 0; it < 8; it++)
        xa[it] = *(const float4*)&X[(size_t)(m0 + lm) * HDIM + it * 16 + lc];

    for (int k0 = 0; k0 < HDIM; k0 += 128) {
        __syncthreads();   // previous compute done reading Xs
        #pragma unroll
        for (int it = 0; it < 8; it++) {
            const int kk = it * 16 + lc;
            Xs[(kk + 0) * 68 + lm] = xa[it].x;
            Xs[(kk + 1) * 68 + lm] = xa[it].y;
            Xs[(kk + 2) * 68 + lm] = xa[it].z;
            Xs[(kk + 3) * 68 + lm] = xa[it].w;
        }
        __syncthreads();
        if (k0 + 128 < HDIM) {       // issue NEXT panel; in flight over compute
            #pragma unroll
            for (int it = 0; it < 8; it++)
                xa[it] = *(const float4*)&X[(size_t)(m0 + lm) * HDIM + k0 + 128 + it * 16 + lc];
        }
        const float* Wp = &W[(size_t)k0 * HDIM + n0 + 4 * tx];
        #pragma unroll 8
        for (int kk = 0; kk < 128; kk++) {
            float4 b4 = *(const float4*)&Wp[(size_t)kk * HDIM];
            float4 a4 = *(const float4*)&Xs[kk * 68 + 4 * ty];
            float a[4] = {a4.x, a4.y, a4.z, a4.w};
            float b[4] = {b4.x, b4.y, b4.z, b4.w};
            #pragma unroll
            for (int ia = 0; ia < 4; ia++)
                #pragma unroll
                for (int ib = 0; ib < 4; ib++)
                    acc[ia][ib] = fmaf(a[ia], b[ib], acc[ia][ib]);
        }
    }
    float4 bv4 = *(const float4*)&bias[n0 + 4 * tx];
    #pragma unroll
    for (int ia = 0; ia < 4; ia++) {
        float4 o;
        o.x = acc[ia][0] + bv4.x; o.y = acc[ia][1] + bv4.y;
        o.z = acc[ia][2] + bv4.z; o.w = acc[ia][3] + bv4.w;
        *(float4*)&out[(size_t)(m0 + 4 * ty + ia) * HDIM + n0 + 4 * tx] = o;
    }
}

// ---------------------------------------------------------------------------
// Kernel B (merged): positional projections (z<24) + content-score GEMM (z>=24).
// pos branch:
//   qp[i,h,e] = sum_d q[i, h*64+d] * Wpk[e*768 + h*64 + d]   (kp analogous)
//   layout (scores_pos consumption order):
//     qp[i*9216 + (e>>5)*384 + ((e>>4)&1)*192 + h*16 + (e&15)]
// cc branch (bias fold, pre-scaled + mask):
//   CC[h,i,j] = ((q[i,h,:]+bpq[h,:]).(k[j,h,:]+bpk[h,:]) - bpq.bpk)/8 + mask[j]
// ---------------------------------------------------------------------------
__global__ __launch_bounds__(256)
void proj_all(const float* __restrict__ q, const float* __restrict__ k,
              const float* __restrict__ Wpk, const float* __restrict__ Wpq,
              const float* __restrict__ bpq, const float* __restrict__ bpk,
              const float* __restrict__ mask,
              float* __restrict__ qp, float* __restrict__ kp,
              float* __restrict__ CC)
{
    __shared__ float As[64][68];   // [d][i]
    __shared__ float Bs[64][68];   // [d][e or j]
    __shared__ float cterm_s;
    const int z = blockIdx.z;
    const int tid = threadIdx.x;
    const int dg = tid % 16, row = tid / 16;
    const int ty = tid / 16, tx = tid % 16;

    if (z < 24) {
        // ---------------- pos_proj branch ----------------
        const int h = z % NHEAD;
        const int s = z / NHEAD;
        const float* Asrc = s ? k   : q;
        const float* Wsrc = s ? Wpq : Wpk;
        float* out        = s ? kp  : qp;
        const int i0 = blockIdx.x * 64, e0 = blockIdx.y * 64;

        #pragma unroll
        for (int r = 0; r < 4; r++) {
            const int rr = r * 16 + row;
            float4 a4 = *(const float4*)&Asrc[(size_t)(i0 + rr) * HDIM + h * 64 + dg * 4];
            float4 b4 = *(const float4*)&Wsrc[(size_t)(e0 + rr) * HDIM + h * 64 + dg * 4];
            As[dg * 4 + 0][rr] = a4.x; As[dg * 4 + 1][rr] = a4.y;
            As[dg * 4 + 2][rr] = a4.z; As[dg * 4 + 3][rr] = a4.w;
            Bs[dg * 4 + 0][rr] = b4.x; Bs[dg * 4 + 1][rr] = b4.y;
            Bs[dg * 4 + 2][rr] = b4.z; Bs[dg * 4 + 3][rr] = b4.w;
        }
        __syncthreads();

        float acc[4][4] = {};
        #pragma unroll 4
        for (int d = 0; d < 64; d++) {
            float4 a4 = *(const float4*)&As[d][4 * ty];
            float4 b4 = *(const float4*)&Bs[d][4 * tx];
            float a[4] = {a4.x, a4.y, a4.z, a4.w};
            float b[4] = {b4.x, b4.y, b4.z, b4.w};
            #pragma unroll
            for (int ia = 0; ia < 4; ia++)
                #pragma unroll
                for (int ib = 0; ib < 4; ib++)
                    acc[ia][ib] = fmaf(a[ia], b[ib], acc[ia][ib]);
        }
        // interleaved store: e = e0 + 4*tx (+0..3) stays in one 16-e group
        const int e = e0 + 4 * tx;
        const int off = (e >> 5) * 384 + ((e >> 4) & 1) * 192 + h * 16 + (e & 15);
        #pragma unroll
        for (int ia = 0; ia < 4; ia++) {
            float4 o = make_float4(acc[ia][0], acc[ia][1], acc[ia][2], acc[ia][3]);
            *(float4*)&out[(size_t)(i0 + 4 * ty + ia) * (NHEAD * HDIM) + off] = o;
        }
    } else {
        // ---------------- cc_gemm branch ----------------
        if (blockIdx.y >= 6) return;
        const int h  = z - 24;
        const int i0 = blockIdx.x * 64, j0 = blockIdx.y * 64;

        const float4 bq4 = *(const float4*)&bpq[h * 64 + dg * 4];
        const float4 bk4 = *(const float4*)&bpk[h * 64 + dg * 4];
        #pragma unroll
        for (int r = 0; r < 4; r++) {
            const int rr = r * 16 + row;
            float4 q4 = *(const float4*)&q[(size_t)(i0 + rr) * HDIM + h * 64 + dg * 4];
            float4 k4 = *(const float4*)&k[(size_t)(j0 + rr) * HDIM + h * 64 + dg * 4];
            As[dg * 4 + 0][rr] = q4.x + bq4.x; As[dg * 4 + 1][rr] = q4.y + bq4.y;
            As[dg * 4 + 2][rr] = q4.z + bq4.z; As[dg * 4 + 3][rr] = q4.w + bq4.w;
            Bs[dg * 4 + 0][rr] = k4.x + bk4.x; Bs[dg * 4 + 1][rr] = k4.y + bk4.y;
            Bs[dg * 4 + 2][rr] = k4.z + bk4.z; Bs[dg * 4 + 3][rr] = k4.w + bk4.w;
        }
        if (tid < 64) {   // wave 0: cterm = bpq[h,:].bpk[h,:]
            float pc = bpq[h * 64 + tid] * bpk[h * 64 + tid];
            #pragma unroll
            for (int o = 32; o; o >>= 1) pc += __shfl_xor(pc, o);
            if (tid == 0) cterm_s = pc;
        }
        __syncthreads();

        float acc[4][4] = {};
        #pragma unroll 4
        for (int d = 0; d < 64; d++) {
            float4 a4 = *(const float4*)&As[d][4 * ty];
            float4 b4 = *(const float4*)&Bs[d][4 * tx];
            float a[4] = {a4.x, a4.y, a4.z, a4.w};
            float b[4] = {b4.x, b4.y, b4.z, b4.w};
            #pragma unroll
            for (int ia = 0; ia < 4; ia++)
                #pragma unroll
                for (int ib = 0; ib < 4; ib++)
                    acc[ia][ib] = fmaf(a[ia], b[ib], acc[ia][ib]);
        }
        const float cterm = cterm_s;
        const float4 m4 = *(const float4*)&mask[j0 + 4 * tx];
        #pragma unroll
        for (int ia = 0; ia < 4; ia++) {
            float4 o;
            o.x = (acc[ia][0] - cterm) * 0.125f + m4.x;
            o.y = (acc[ia][1] - cterm) * 0.125f + m4.y;
            o.z = (acc[ia][2] - cterm) * 0.125f + m4.z;
            o.w = (acc[ia][3] - cterm) * 0.125f + m4.w;
            *(float4*)&CC[((size_t)h * SEQ + i0 + 4 * ty + ia) * SEQ + j0 + 4 * tx] = o;
        }
    }
}

// ---------------------------------------------------------------------------
// Kernel C v5: single pass over pos_emb (453 MB), double-buffered LDS.
// Block (i, jh) handles j in [jh*192, jh*192+192):
//   A1 [h*S*S + i*S + j] = 0.125 * sum_e pe[i,j,e] * qp[i,h,e]
//   P2T[h*S*S + i*S + j] = 0.125 * sum_e pe[i,j,e] * kp[i,h,e]
// v5: two LDS buffers (2x25.6 KB = 51.2 KB; 3 blocks/CU = 153.6 <= 160 KiB)
// -> ONE barrier per chunk (24 vs 48) and ds_write of chunk c+1 overlaps
// compute of chunk c.  Register prefetch keeps ~24-48 KB/block of pe loads
// in flight through every compute phase.
// ---------------------------------------------------------------------------
__global__ __launch_bounds__(256, 3)
void scores_pos(const float* __restrict__ pe, const float* __restrict__ qp,
                const float* __restrict__ kp,
                float* __restrict__ A1, float* __restrict__ P2T)
{
    __shared__ float lds[2 * LDSB];   // two Ps chunks [e][192+pad8]; buf0 reused as Acc[24][200]
    const int i    = blockIdx.x;
    const int jh   = blockIdx.y;      // 0,1
    const int tid  = threadIdx.x;
    const int lane = tid & 63;
    const int wave = tid >> 6;
    const int rgu = __builtin_amdgcn_readfirstlane(wave >> 1);
    const int esu = __builtin_amdgcn_readfirstlane(wave & 1);

    const float* pebase = pe + ((size_t)i * SEQ + jh * 192) * HDIM;
    const float* wb = (rgu ? kp : qp) + (size_t)i * NHEAD * HDIM;

    const int wr  = tid >> 3;       // 0..31 (local j pair base /2)
    const int wec = tid & 7;        // 0..7  (float4 within 32-e chunk)

    float acc[12][3] = {};
    float4 ga[6], gb[6];

    auto loadc = [&](float4* g, int c) {
        const int e0 = c * 32;
        #pragma unroll
        for (int rnd = 0; rnd < 3; rnd++) {
            const int jb = rnd * 64 + wr * 2;
            g[2 * rnd + 0] = *(const float4*)&pebase[(size_t)jb * HDIM + e0 + wec * 4];
            g[2 * rnd + 1] = *(const float4*)&pebase[(size_t)(jb + 1) * HDIM + e0 + wec * 4];
        }
    };
    auto writec = [&](float* buf, const float4* g) {
        #pragma unroll
        for (int rnd = 0; rnd < 3; rnd++) {
            const int jb = rnd * 64 + wr * 2;
            const float4 g0 = g[2 * rnd], g1 = g[2 * rnd + 1];
            *(float2*)&buf[(wec * 4 + 0) * 200 + jb] = make_float2(g0.x, g1.x);
            *(float2*)&buf[(wec * 4 + 1) * 200 + jb] = make_float2(g0.y, g1.y);
            *(float2*)&buf[(wec * 4 + 2) * 200 + jb] = make_float2(g0.z, g1.z);
            *(float2*)&buf[(wec * 4 + 3) * 200 + jb] = make_float2(g0.w, g1.w);
        }
    };
    auto compute = [&](const float* buf, int c) {
        // contiguous 192-float slab for this (chunk, e-half): w[r*16 + ee]
        const float* wc = wb + c * 384 + esu * 192;
        #pragma unroll 4
        for (int ee = 0; ee < 16; ee++) {
            const int ei = esu * 16 + ee;
            float2 p2 = *(const float2*)&buf[ei * 200 + 2 * lane];
            float  p1 = buf[ei * 200 + 128 + lane];
            #pragma unroll
            for (int r = 0; r < 12; r++) {
                const float w = wc[r * 16 + ee];
                acc[r][0] = fmaf(w, p2.x, acc[r][0]);
                acc[r][1] = fmaf(w, p2.y, acc[r][1]);
                acc[r][2] = fmaf(w, p1,   acc[r][2]);
            }
        }
    };

    float* buf0 = lds;
    float* buf1 = lds + LDSB;

    loadc(ga, 0);
    loadc(gb, 1);
    writec(buf0, ga);            // chunk 0 (waits only ga's 6 loads)
    __syncthreads();
    #pragma unroll 1
    for (int cc = 0; cc < 12; cc++) {
        const int c0 = 2 * cc, c1 = 2 * cc + 1;
        if (cc < 11) loadc(ga, c0 + 2);     // in flight over write+compute
        writec(buf1, gb);                   // chunk c1 -> buf1 (overlaps compute c0)
        compute(buf0, c0);
        __syncthreads();
        if (cc < 11) {
            loadc(gb, c1 + 2);
            writec(buf0, ga);               // chunk c0+2 -> buf0 (overlaps compute c1)
        }
        compute(buf1, c1);
        __syncthreads();
    }

    // Combine the two e-half partials through LDS (Acc[24][200] aliases buf0).
    if (esu == 1) {
        #pragma unroll
        for (int r = 0; r < 12; r++) {
            const int row = rgu * 12 + r;
            *(float2*)&buf0[row * 200 + 2 * lane] = make_float2(acc[r][0], acc[r][1]);
            buf0[row * 200 + 128 + lane] = acc[r][2];
        }
    }
    __syncthreads();
    if (esu == 0) {
        #pragma unroll
        for (int r = 0; r < 12; r++) {
            const int row = rgu * 12 + r;
            float2 o2 = *(const float2*)&buf0[row * 200 + 2 * lane];
            float  o1 = buf0[row * 200 + 128 + lane];
            o2.x += acc[r][0]; o2.y += acc[r][1]; o1 += acc[r][2];
            *(float2*)&buf0[row * 200 + 2 * lane] = o2;
            buf0[row * 200 + 128 + lane] = o1;
        }
    }
    __syncthreads();

    // Coalesced pure stores: rows 0..11 -> A1, rows 12..23 -> P2T (both /8).
    for (int t = tid; t < 24 * 48; t += 256) {
        const int row = t / 48;
        const int c4  = (t % 48) * 4;
        float4 o = *(const float4*)&buf0[row * 200 + c4];
        o.x *= 0.125f; o.y *= 0.125f; o.z *= 0.125f; o.w *= 0.125f;
        float* dst = (row < 12)
            ? &A1[((size_t)row * SEQ + i) * SEQ + jh * 192 + c4]
            : &P2T[((size_t)(row - 12) * SEQ + i) * SEQ + jh * 192 + c4];
        *(float4*)dst = o;
    }
}

// ---------------------------------------------------------------------------
// Kernel D v5: softmax + PV for GI=4 i-rows per block.
//   sc[g][j] = CC[h,i0+g,j] + A1[h,i0+g,j] + P2T[h,j,i0+g]
// P2T column loads for the 4 rows collapse into ONE float4 per thread
// (consecutive i).  PV reuses each v load for 4 rows IN REGISTERS.
// grid (96, 12), block 384 (thread=j).
// ---------------------------------------------------------------------------
__global__ __launch_bounds__(384)
void attn_out(const float* __restrict__ CC, const float* __restrict__ A1,
              const float* __restrict__ P2T, const float* __restrict__ v,
              float* __restrict__ out)
{
    const int i0 = blockIdx.x * GI, h = blockIdx.y;
    const int tid = threadIdx.x;   // = j
    __shared__ float p_s[GI][SEQ];
    __shared__ float redm[GI][6], reds[GI][6];
    __shared__ float redvf[GI][24 * 64];

    const int lane = tid & 63, w = tid >> 6;

    // scores: one float4 covers the P2T column entries for all 4 rows
    float4 t4 = *(const float4*)&P2T[((size_t)h * SEQ + tid) * SEQ + i0];
    float tt[GI] = {t4.x, t4.y, t4.z, t4.w};
    float sc[GI];
    #pragma unroll
    for (int g = 0; g < GI; g++) {
        const size_t off = ((size_t)h * SEQ + i0 + g) * SEQ + tid;
        sc[g] = CC[off] + A1[off] + tt[g];
    }

    // per-row softmax (4 independent wave reductions)
    #pragma unroll
    for (int g = 0; g < GI; g++) {
        float m = sc[g];
        #pragma unroll
        for (int o = 32; o; o >>= 1) m = fmaxf(m, __shfl_xor(m, o));
        if (lane == 0) redm[g][w] = m;
    }
    __syncthreads();
    float SUMv[GI];
    #pragma unroll
    for (int g = 0; g < GI; g++) {
        float m = redm[g][0];
        #pragma unroll
        for (int t = 1; t < 6; t++) m = fmaxf(m, redm[g][t]);
        float p = __expf(sc[g] - m);
        float sum = p;
        #pragma unroll
        for (int o = 32; o; o >>= 1) sum += __shfl_xor(sum, o);
        if (lane == 0) reds[g][w] = sum;
        p_s[g][tid] = p;
    }
    __syncthreads();
    #pragma unroll
    for (int g = 0; g < GI; g++)
        SUMv[g] = reds[g][0] + reds[g][1] + reds[g][2] +
                  reds[g][3] + reds[g][4] + reds[g][5];

    // PV phase: wave w covers j in [64w,64w+64); one v load feeds 4 rows.
    const int dq = lane & 15, jsub = lane >> 4;
    const int j0 = w * 64;
    float4 av[GI] = {};
    #pragma unroll 4
    for (int jj = 0; jj < 16; jj++) {
        const int j = j0 + jj * 4 + jsub;
        float4 v4 = *(const float4*)&v[(size_t)j * HDIM + h * 64 + dq * 4];
        #pragma unroll
        for (int g = 0; g < GI; g++) {
            const float pj = p_s[g][j];
            av[g].x = fmaf(pj, v4.x, av[g].x); av[g].y = fmaf(pj, v4.y, av[g].y);
            av[g].z = fmaf(pj, v4.z, av[g].z); av[g].w = fmaf(pj, v4.w, av[g].w);
        }
    }
    #pragma unroll
    for (int g = 0; g < GI; g++)
        *(float4*)&redvf[g][(w * 4 + jsub) * 64 + dq * 4] = av[g];
    __syncthreads();
    if (tid < 64) {
        #pragma unroll
        for (int g = 0; g < GI; g++) {
            float o = 0.f;
            #pragma unroll
            for (int r = 0; r < 24; r++) o += redvf[g][r * 64 + tid];
            out[(size_t)(i0 + g) * HDIM + h * 64 + tid] = o / SUMv[g];
        }
    }
}

// ---------------------------------------------------------------------------
extern "C" void kernel_launch(void* const* d_in, const int* in_sizes, int n_in,
                              void* d_out, int out_size, void* d_ws, size_t ws_size,
                              hipStream_t stream)
{
    const float* hs   = (const float*)d_in[0];
    const float* mask = (const float*)d_in[1];
    const float* pe   = (const float*)d_in[2];
    const float* Wq   = (const float*)d_in[3];
    const float* bq   = (const float*)d_in[4];
    const float* Wk   = (const float*)d_in[5];
    const float* bk   = (const float*)d_in[6];
    const float* Wv   = (const float*)d_in[7];
    const float* bv   = (const float*)d_in[8];
    const float* Wpk  = (const float*)d_in[9];
    const float* bpk  = (const float*)d_in[10];
    const float* Wpq  = (const float*)d_in[11];
    const float* bpq  = (const float*)d_in[12];

    float* ws = (float*)d_ws;
    const size_t SZ_QKV = (size_t)SEQ * HDIM;            // 294912
    const size_t SZ_QP  = (size_t)SEQ * NHEAD * HDIM;    // 3538944
    const size_t SZ_SC  = (size_t)NHEAD * SEQ * SEQ;     // 1769472
    float* q   = ws;
    float* k   = q  + SZ_QKV;
    float* v   = k  + SZ_QKV;
    float* qp  = v  + SZ_QKV;
    float* kp  = qp + SZ_QP;
    float* A1  = kp + SZ_QP;
    float* P2T = A1 + SZ_SC;
    float* CC  = P2T + SZ_SC;

    qkv_gemm<<<dim3(6, 12, 3), 256, 0, stream>>>(hs, Wq, bq, Wk, bk, Wv, bv, q, k, v);
    proj_all<<<dim3(6, 12, 36), 256, 0, stream>>>(q, k, Wpk, Wpq, bpq, bpk, mask,
                                                  qp, kp, CC);
    scores_pos<<<dim3(SEQ, 2), 256, 0, stream>>>(pe, qp, kp, A1, P2T);
    attn_out<<<dim3(SEQ / GI, NHEAD), 384, 0, stream>>>(CC, A1, P2T, v, (float*)d_out);
}

// Round 5
// 782.922 us; speedup vs baseline: 1.2636x; 1.2636x over previous
//
#include <hip/hip_runtime.h>
#include <math.h>

// Problem constants
#define SEQ 384
#define HDIM 768
#define NHEAD 12
#define DHEAD 64
#define GI 4   // i-rows per attn_out block (v reused in registers)

// ---------------------------------------------------------------------------
// Kernel A: fused QKV projection.  C = X @ W + b for W in {Wq,Wk,Wv}
// X staged in LDS (k-panels of 128, transposed), W streamed from L2.
// grid (6 mtiles, 12 ntiles, 3 matrices), block 256, tile 64x64.
// ---------------------------------------------------------------------------
__global__ __launch_bounds__(256)
void qkv_gemm(const float* __restrict__ X,
              const float* __restrict__ Wq, const float* __restrict__ bq,
              const float* __restrict__ Wk, const float* __restrict__ bk,
              const float* __restrict__ Wv, const float* __restrict__ bv,
              float* __restrict__ q, float* __restrict__ k, float* __restrict__ v)
{
    __shared__ float Xs[128 * 68];   // [k][m], padded stride 68
    const int z = blockIdx.z;
    const float* W    = (z == 0) ? Wq : (z == 1) ? Wk : Wv;
    const float* bias = (z == 0) ? bq : (z == 1) ? bk : bv;
    float* out        = (z == 0) ? q  : (z == 1) ? k  : v;

    const int m0 = blockIdx.x * 64;
    const int n0 = blockIdx.y * 64;
    const int tid = threadIdx.x;
    const int ty = tid / 16, tx = tid % 16;

    const int lm = tid >> 2;          // 0..63 (m row)
    const int lc = (tid & 3) * 4;     // 0,4,8,12 (k sub-col)

    float acc[4][4] = {};

    for (int k0 = 0; k0 < HDIM; k0 += 128) {
        float4 xa[8];
        #pragma unroll
        for (int it = 0; it < 8; it++)
            xa[it] = *(const float4*)&X[(size_t)(m0 + lm) * HDIM + k0 + it * 16 + lc];
        __syncthreads();
        #pragma unroll
        for (int it = 0; it < 8; it++) {
            const int kk = it * 16 + lc;
            Xs[(kk + 0) * 68 + lm] = xa[it].x;
            Xs[(kk + 1) * 68 + lm] = xa[it].y;
            Xs[(kk + 2) * 68 + lm] = xa[it].z;
            Xs[(kk + 3) * 68 + lm] = xa[it].w;
        }
        __syncthreads();
        const float* Wp = &W[(size_t)k0 * HDIM + n0 + 4 * tx];
        #pragma unroll 8
        for (int kk = 0; kk < 128; kk++) {
            float4 b4 = *(const float4*)&Wp[(size_t)kk * HDIM];
            float4 a4 = *(const float4*)&Xs[kk * 68 + 4 * ty];
            float a[4] = {a4.x, a4.y, a4.z, a4.w};
            float b[4] = {b4.x, b4.y, b4.z, b4.w};
            #pragma unroll
            for (int ia = 0; ia < 4; ia++)
                #pragma unroll
                for (int ib = 0; ib < 4; ib++)
                    acc[ia][ib] = fmaf(a[ia], b[ib], acc[ia][ib]);
        }
    }
    float4 bv4 = *(const float4*)&bias[n0 + 4 * tx];
    #pragma unroll
    for (int ia = 0; ia < 4; ia++) {
        float4 o;
        o.x = acc[ia][0] + bv4.x; o.y = acc[ia][1] + bv4.y;
        o.z = acc[ia][2] + bv4.z; o.w = acc[ia][3] + bv4.w;
        *(float4*)&out[(size_t)(m0 + 4 * ty + ia) * HDIM + n0 + 4 * tx] = o;
    }
}

// ---------------------------------------------------------------------------
// Kernel B (merged): positional projections (z<24) + content-score GEMM (z>=24).
// pos branch:
//   qp[i,h,e] = sum_d q[i, h*64+d] * Wpk[e*768 + h*64 + d]   (kp analogous)
//   layout (scores_pos consumption order):
//     qp[i*9216 + (e>>5)*384 + ((e>>4)&1)*192 + h*16 + (e&15)]
//   so each (chunk, e-half) slab of 12h x 16e = 768 B is CONTIGUOUS ->
//   scores_pos's wave-uniform w reads become batched s_load
//   (was: 12 cold scalar lines at 3KB stride interleaved into the FMA loop).
// cc branch (bias fold, pre-scaled + mask):
//   CC[h,i,j] = ((q[i,h,:]+bpq[h,:]).(k[j,h,:]+bpk[h,:]) - bpq.bpk)/8 + mask[j]
// ---------------------------------------------------------------------------
__global__ __launch_bounds__(256)
void proj_all(const float* __restrict__ q, const float* __restrict__ k,
              const float* __restrict__ Wpk, const float* __restrict__ Wpq,
              const float* __restrict__ bpq, const float* __restrict__ bpk,
              const float* __restrict__ mask,
              float* __restrict__ qp, float* __restrict__ kp,
              float* __restrict__ CC)
{
    __shared__ float As[64][68];   // [d][i]
    __shared__ float Bs[64][68];   // [d][e or j]
    __shared__ float cterm_s;
    const int z = blockIdx.z;
    const int tid = threadIdx.x;
    const int dg = tid % 16, row = tid / 16;
    const int ty = tid / 16, tx = tid % 16;

    if (z < 24) {
        // ---------------- pos_proj branch ----------------
        const int h = z % NHEAD;
        const int s = z / NHEAD;
        const float* Asrc = s ? k   : q;
        const float* Wsrc = s ? Wpq : Wpk;
        float* out        = s ? kp  : qp;
        const int i0 = blockIdx.x * 64, e0 = blockIdx.y * 64;

        #pragma unroll
        for (int r = 0; r < 4; r++) {
            const int rr = r * 16 + row;
            float4 a4 = *(const float4*)&Asrc[(size_t)(i0 + rr) * HDIM + h * 64 + dg * 4];
            float4 b4 = *(const float4*)&Wsrc[(size_t)(e0 + rr) * HDIM + h * 64 + dg * 4];
            As[dg * 4 + 0][rr] = a4.x; As[dg * 4 + 1][rr] = a4.y;
            As[dg * 4 + 2][rr] = a4.z; As[dg * 4 + 3][rr] = a4.w;
            Bs[dg * 4 + 0][rr] = b4.x; Bs[dg * 4 + 1][rr] = b4.y;
            Bs[dg * 4 + 2][rr] = b4.z; Bs[dg * 4 + 3][rr] = b4.w;
        }
        __syncthreads();

        float acc[4][4] = {};
        #pragma unroll 4
        for (int d = 0; d < 64; d++) {
            float4 a4 = *(const float4*)&As[d][4 * ty];
            float4 b4 = *(const float4*)&Bs[d][4 * tx];
            float a[4] = {a4.x, a4.y, a4.z, a4.w};
            float b[4] = {b4.x, b4.y, b4.z, b4.w};
            #pragma unroll
            for (int ia = 0; ia < 4; ia++)
                #pragma unroll
                for (int ib = 0; ib < 4; ib++)
                    acc[ia][ib] = fmaf(a[ia], b[ib], acc[ia][ib]);
        }
        // interleaved store: e = e0 + 4*tx (+0..3) stays in one 16-e group
        const int e = e0 + 4 * tx;
        const int off = (e >> 5) * 384 + ((e >> 4) & 1) * 192 + h * 16 + (e & 15);
        #pragma unroll
        for (int ia = 0; ia < 4; ia++) {
            float4 o = make_float4(acc[ia][0], acc[ia][1], acc[ia][2], acc[ia][3]);
            *(float4*)&out[(size_t)(i0 + 4 * ty + ia) * (NHEAD * HDIM) + off] = o;
        }
    } else {
        // ---------------- cc_gemm branch ----------------
        if (blockIdx.y >= 6) return;
        const int h  = z - 24;
        const int i0 = blockIdx.x * 64, j0 = blockIdx.y * 64;

        const float4 bq4 = *(const float4*)&bpq[h * 64 + dg * 4];
        const float4 bk4 = *(const float4*)&bpk[h * 64 + dg * 4];
        #pragma unroll
        for (int r = 0; r < 4; r++) {
            const int rr = r * 16 + row;
            float4 q4 = *(const float4*)&q[(size_t)(i0 + rr) * HDIM + h * 64 + dg * 4];
            float4 k4 = *(const float4*)&k[(size_t)(j0 + rr) * HDIM + h * 64 + dg * 4];
            As[dg * 4 + 0][rr] = q4.x + bq4.x; As[dg * 4 + 1][rr] = q4.y + bq4.y;
            As[dg * 4 + 2][rr] = q4.z + bq4.z; As[dg * 4 + 3][rr] = q4.w + bq4.w;
            Bs[dg * 4 + 0][rr] = k4.x + bk4.x; Bs[dg * 4 + 1][rr] = k4.y + bk4.y;
            Bs[dg * 4 + 2][rr] = k4.z + bk4.z; Bs[dg * 4 + 3][rr] = k4.w + bk4.w;
        }
        if (tid < 64) {   // wave 0: cterm = bpq[h,:].bpk[h,:]
            float pc = bpq[h * 64 + tid] * bpk[h * 64 + tid];
            #pragma unroll
            for (int o = 32; o; o >>= 1) pc += __shfl_xor(pc, o);
            if (tid == 0) cterm_s = pc;
        }
        __syncthreads();

        float acc[4][4] = {};
        #pragma unroll 4
        for (int d = 0; d < 64; d++) {
            float4 a4 = *(const float4*)&As[d][4 * ty];
            float4 b4 = *(const float4*)&Bs[d][4 * tx];
            float a[4] = {a4.x, a4.y, a4.z, a4.w};
            float b[4] = {b4.x, b4.y, b4.z, b4.w};
            #pragma unroll
            for (int ia = 0; ia < 4; ia++)
                #pragma unroll
                for (int ib = 0; ib < 4; ib++)
                    acc[ia][ib] = fmaf(a[ia], b[ib], acc[ia][ib]);
        }
        const float cterm = cterm_s;
        const float4 m4 = *(const float4*)&mask[j0 + 4 * tx];
        #pragma unroll
        for (int ia = 0; ia < 4; ia++) {
            float4 o;
            o.x = (acc[ia][0] - cterm) * 0.125f + m4.x;
            o.y = (acc[ia][1] - cterm) * 0.125f + m4.y;
            o.z = (acc[ia][2] - cterm) * 0.125f + m4.z;
            o.w = (acc[ia][3] - cterm) * 0.125f + m4.w;
            *(float4*)&CC[((size_t)h * SEQ + i0 + 4 * ty + ia) * SEQ + j0 + 4 * tx] = o;
        }
    }
}

// ---------------------------------------------------------------------------
// Kernel C: single pass over pos_emb (453 MB), software-pipelined.
// Block (i, jh) handles j in [jh*192, jh*192+192):
//   A1 [h*S*S + i*S + j] = 0.125 * sum_e pe[i,j,e] * qp[i,h,e]
//   P2T[h*S*S + i*S + j] = 0.125 * sum_e pe[i,j,e] * kp[i,h,e]
// Single LDS buffer (25.6 KB -> 3 blocks/CU with headroom); double-buffered
// REGISTER prefetch keeps up to 48 KB/block of pe loads in flight through
// the compute phases.  w (qp/kp) read via wave-uniform scalar loads from the
// contiguous half-chunk layout (768 B slabs).
// ---------------------------------------------------------------------------
__global__ __launch_bounds__(256, 3)
void scores_pos(const float* __restrict__ pe, const float* __restrict__ qp,
                const float* __restrict__ kp,
                float* __restrict__ A1, float* __restrict__ P2T)
{
    __shared__ float lds[32 * 200];   // Ps chunk [e][192 +pad8]; reused Acc[24][200]
    const int i    = blockIdx.x;
    const int jh   = blockIdx.y;      // 0,1
    const int tid  = threadIdx.x;
    const int lane = tid & 63;
    const int wave = tid >> 6;
    const int rgu = __builtin_amdgcn_readfirstlane(wave >> 1);
    const int esu = __builtin_amdgcn_readfirstlane(wave & 1);

    const float* pebase = pe + ((size_t)i * SEQ + jh * 192) * HDIM;
    const float* wb = (rgu ? kp : qp) + (size_t)i * NHEAD * HDIM;

    const int wr  = tid >> 3;       // 0..31 (local j pair base /2)
    const int wec = tid & 7;        // 0..7  (float4 within 32-e chunk)

    float acc[12][3] = {};
    float4 ga[6], gb[6];

    auto loadc = [&](float4* g, int c) {
        const int e0 = c * 32;
        #pragma unroll
        for (int rnd = 0; rnd < 3; rnd++) {
            const int jb = rnd * 64 + wr * 2;
            g[2 * rnd + 0] = *(const float4*)&pebase[(size_t)jb * HDIM + e0 + wec * 4];
            g[2 * rnd + 1] = *(const float4*)&pebase[(size_t)(jb + 1) * HDIM + e0 + wec * 4];
        }
    };
    auto writec = [&](const float4* g) {
        #pragma unroll
        for (int rnd = 0; rnd < 3; rnd++) {
            const int jb = rnd * 64 + wr * 2;
            const float4 g0 = g[2 * rnd], g1 = g[2 * rnd + 1];
            *(float2*)&lds[(wec * 4 + 0) * 200 + jb] = make_float2(g0.x, g1.x);
            *(float2*)&lds[(wec * 4 + 1) * 200 + jb] = make_float2(g0.y, g1.y);
            *(float2*)&lds[(wec * 4 + 2) * 200 + jb] = make_float2(g0.z, g1.z);
            *(float2*)&lds[(wec * 4 + 3) * 200 + jb] = make_float2(g0.w, g1.w);
        }
    };
    auto compute = [&](int c) {
        // contiguous 192-float slab for this (chunk, e-half): w[r*16 + ee]
        const float* wc = wb + c * 384 + esu * 192;
        #pragma unroll 4
        for (int ee = 0; ee < 16; ee++) {
            const int ei = esu * 16 + ee;
            float2 p2 = *(const float2*)&lds[ei * 200 + 2 * lane];
            float  p1 = lds[ei * 200 + 128 + lane];
            #pragma unroll
            for (int r = 0; r < 12; r++) {
                const float w = wc[r * 16 + ee];
                acc[r][0] = fmaf(w, p2.x, acc[r][0]);
                acc[r][1] = fmaf(w, p2.y, acc[r][1]);
                acc[r][2] = fmaf(w, p1,   acc[r][2]);
            }
        }
    };

    loadc(ga, 0);
    #pragma unroll 1
    for (int cc = 0; cc < 12; cc++) {
        loadc(gb, 2 * cc + 1);          // in flight across write(ga)+compute(2cc)
        __syncthreads();                // previous chunk's readers done
        writec(ga);                     // waits only ga's 6 loads (vmcnt)
        __syncthreads();
        if (cc < 11) loadc(ga, 2 * cc + 2);   // 2-ahead prefetch
        compute(2 * cc);
        __syncthreads();
        writec(gb);
        __syncthreads();
        compute(2 * cc + 1);
    }

    // Combine the two e-half partials through LDS (Acc[24][200] aliases Ps).
    __syncthreads();
    if (esu == 1) {
        #pragma unroll
        for (int r = 0; r < 12; r++) {
            const int row = rgu * 12 + r;
            *(float2*)&lds[row * 200 + 2 * lane] = make_float2(acc[r][0], acc[r][1]);
            lds[row * 200 + 128 + lane] = acc[r][2];
        }
    }
    __syncthreads();
    if (esu == 0) {
        #pragma unroll
        for (int r = 0; r < 12; r++) {
            const int row = rgu * 12 + r;
            float2 o2 = *(const float2*)&lds[row * 200 + 2 * lane];
            float  o1 = lds[row * 200 + 128 + lane];
            o2.x += acc[r][0]; o2.y += acc[r][1]; o1 += acc[r][2];
            *(float2*)&lds[row * 200 + 2 * lane] = o2;
            lds[row * 200 + 128 + lane] = o1;
        }
    }
    __syncthreads();

    // Coalesced pure stores: rows 0..11 -> A1, rows 12..23 -> P2T (both /8).
    for (int t = tid; t < 24 * 48; t += 256) {
        const int row = t / 48;
        const int c4  = (t % 48) * 4;
        float4 o = *(const float4*)&lds[row * 200 + c4];
        o.x *= 0.125f; o.y *= 0.125f; o.z *= 0.125f; o.w *= 0.125f;
        float* dst = (row < 12)
            ? &A1[((size_t)row * SEQ + i) * SEQ + jh * 192 + c4]
            : &P2T[((size_t)(row - 12) * SEQ + i) * SEQ + jh * 192 + c4];
        *(float4*)dst = o;
    }
}

// ---------------------------------------------------------------------------
// Kernel D v5: softmax + PV for GI=4 i-rows per block.
//   sc[g][j] = CC[h,i0+g,j] + A1[h,i0+g,j] + P2T[h,j,i0+g]
// P2T column loads for the 4 rows collapse into ONE float4 per thread
// (consecutive i).  PV reuses each v load for 4 rows IN REGISTERS ->
// v L2 traffic /4 (452 MB -> 113 MB).  grid (96, 12), block 384 (thread=j).
// ---------------------------------------------------------------------------
__global__ __launch_bounds__(384)
void attn_out(const float* __restrict__ CC, const float* __restrict__ A1,
              const float* __restrict__ P2T, const float* __restrict__ v,
              float* __restrict__ out)
{
    const int i0 = blockIdx.x * GI, h = blockIdx.y;
    const int tid = threadIdx.x;   // = j
    __shared__ float p_s[GI][SEQ];
    __shared__ float redm[GI][6], reds[GI][6];
    __shared__ float redvf[GI][24 * 64];

    const int lane = tid & 63, w = tid >> 6;

    // scores: one float4 covers the P2T column entries for all 4 rows
    float4 t4 = *(const float4*)&P2T[((size_t)h * SEQ + tid) * SEQ + i0];
    float tt[GI] = {t4.x, t4.y, t4.z, t4.w};
    float sc[GI];
    #pragma unroll
    for (int g = 0; g < GI; g++) {
        const size_t off = ((size_t)h * SEQ + i0 + g) * SEQ + tid;
        sc[g] = CC[off] + A1[off] + tt[g];
    }

    // per-row softmax (4 independent wave reductions)
    #pragma unroll
    for (int g = 0; g < GI; g++) {
        float m = sc[g];
        #pragma unroll
        for (int o = 32; o; o >>= 1) m = fmaxf(m, __shfl_xor(m, o));
        if (lane == 0) redm[g][w] = m;
    }
    __syncthreads();
    float SUMv[GI];
    #pragma unroll
    for (int g = 0; g < GI; g++) {
        float m = redm[g][0];
        #pragma unroll
        for (int t = 1; t < 6; t++) m = fmaxf(m, redm[g][t]);
        float p = __expf(sc[g] - m);
        float sum = p;
        #pragma unroll
        for (int o = 32; o; o >>= 1) sum += __shfl_xor(sum, o);
        if (lane == 0) reds[g][w] = sum;
        p_s[g][tid] = p;
    }
    __syncthreads();
    #pragma unroll
    for (int g = 0; g < GI; g++)
        SUMv[g] = reds[g][0] + reds[g][1] + reds[g][2] +
                  reds[g][3] + reds[g][4] + reds[g][5];

    // PV phase: wave w covers j in [64w,64w+64); one v load feeds 4 rows.
    const int dq = lane & 15, jsub = lane >> 4;
    const int j0 = w * 64;
    float4 av[GI] = {};
    #pragma unroll 4
    for (int jj = 0; jj < 16; jj++) {
        const int j = j0 + jj * 4 + jsub;
        float4 v4 = *(const float4*)&v[(size_t)j * HDIM + h * 64 + dq * 4];
        #pragma unroll
        for (int g = 0; g < GI; g++) {
            const float pj = p_s[g][j];
            av[g].x = fmaf(pj, v4.x, av[g].x); av[g].y = fmaf(pj, v4.y, av[g].y);
            av[g].z = fmaf(pj, v4.z, av[g].z); av[g].w = fmaf(pj, v4.w, av[g].w);
        }
    }
    #pragma unroll
    for (int g = 0; g < GI; g++)
        *(float4*)&redvf[g][(w * 4 + jsub) * 64 + dq * 4] = av[g];
    __syncthreads();
    if (tid < 64) {
        #pragma unroll
        for (int g = 0; g < GI; g++) {
            float o = 0.f;
            #pragma unroll
            for (int r = 0; r < 24; r++) o += redvf[g][r * 64 + tid];
            out[(size_t)(i0 + g) * HDIM + h * 64 + tid] = o / SUMv[g];
        }
    }
}

// ---------------------------------------------------------------------------
extern "C" void kernel_launch(void* const* d_in, const int* in_sizes, int n_in,
                              void* d_out, int out_size, void* d_ws, size_t ws_size,
                              hipStream_t stream)
{
    const float* hs   = (const float*)d_in[0];
    const float* mask = (const float*)d_in[1];
    const float* pe   = (const float*)d_in[2];
    const float* Wq   = (const float*)d_in[3];
    const float* bq   = (const float*)d_in[4];
    const float* Wk   = (const float*)d_in[5];
    const float* bk   = (const float*)d_in[6];
    const float* Wv   = (const float*)d_in[7];
    const float* bv   = (const float*)d_in[8];
    const float* Wpk  = (const float*)d_in[9];
    const float* bpk  = (const float*)d_in[10];
    const float* Wpq  = (const float*)d_in[11];
    const float* bpq  = (const float*)d_in[12];

    float* ws = (float*)d_ws;
    const size_t SZ_QKV = (size_t)SEQ * HDIM;            // 294912
    const size_t SZ_QP  = (size_t)SEQ * NHEAD * HDIM;    // 3538944
    const size_t SZ_SC  = (size_t)NHEAD * SEQ * SEQ;     // 1769472
    float* q   = ws;
    float* k   = q  + SZ_QKV;
    float* v   = k  + SZ_QKV;
    float* qp  = v  + SZ_QKV;
    float* kp  = qp + SZ_QP;
    float* A1  = kp + SZ_QP;
    float* P2T = A1 + SZ_SC;
    float* CC  = P2T + SZ_SC;

    qkv_gemm<<<dim3(6, 12, 3), 256, 0, stream>>>(hs, Wq, bq, Wk, bk, Wv, bv, q, k, v);
    proj_all<<<dim3(6, 12, 36), 256, 0, stream>>>(q, k, Wpk, Wpq, bpq, bpk, mask,
                                                  qp, kp, CC);
    scores_pos<<<dim3(SEQ, 2), 256, 0, stream>>>(pe, qp, kp, A1, P2T);
    attn_out<<<dim3(SEQ / GI, NHEAD), 384, 0, stream>>>(CC, A1, P2T, v, (float*)d_out);
}